// Round 10
// baseline (462.042 us; speedup 1.0000x reference)
//
#include <hip/hip_runtime.h>
#include <hip/hip_bf16.h>

typedef __attribute__((ext_vector_type(8))) short short8;
typedef __attribute__((ext_vector_type(4))) float f32x4;

__device__ __forceinline__ unsigned short fbf(float f) {
  union { float f; unsigned u; } v; v.f = f;
  unsigned r = v.u + 0x7fffu + ((v.u >> 16) & 1u);   // RNE
  return (unsigned short)(r >> 16);
}
__device__ __forceinline__ unsigned pk2(float a, float b) {
  return (unsigned)fbf(a) | ((unsigned)fbf(b) << 16);
}
__device__ __forceinline__ float ubf(unsigned hi) {   // bf16 bits (low16) -> float
  union { unsigned u; float f; } v; v.u = hi << 16; return v.f;
}
__device__ __forceinline__ float dot4(float4 a, float4 b) {
  return fmaf(a.x, b.x, fmaf(a.y, b.y, fmaf(a.z, b.z, a.w * b.w)));
}

// -------- phase1: degree count + A_s/A_d tables + x->bf16 (single x pass) --------
__launch_bounds__(256)
__global__ void k_phase1(const float* __restrict__ x, const float* __restrict__ W_att,
                         const int* __restrict__ edst, int E,
                         float4* __restrict__ A_s, float4* __restrict__ A_d,
                         unsigned* __restrict__ xb32, int* __restrict__ deg, int N) {
  __shared__ float4 s_wa[160];                 // 4 heads x 40 float4 (row len 160)
  if (threadIdx.x < 160) s_wa[threadIdx.x] = ((const float4*)W_att)[threadIdx.x];
  for (int i = blockIdx.x * blockDim.x + threadIdx.x; i < E; i += gridDim.x * blockDim.x)
    atomicAdd(&deg[edst[i]], 1);
  __syncthreads();
  for (int v = blockIdx.x * blockDim.x + threadIdx.x; v < N; v += gridDim.x * blockDim.x) {
    const float4* xp = (const float4*)&x[v * 64];
    float4 xq[16];
    #pragma unroll
    for (int k = 0; k < 16; k++) xq[k] = xp[k];
    float as[4] = {}, ad[4] = {};
    #pragma unroll
    for (int h = 0; h < 4; h++) {
      #pragma unroll
      for (int k = 0; k < 16; k++) {
        as[h] += dot4(s_wa[h * 40 + k], xq[k]);
        ad[h] += dot4(s_wa[h * 40 + 16 + k], xq[k]);
      }
    }
    A_s[v] = make_float4(as[0], as[1], as[2], as[3]);
    A_d[v] = make_float4(ad[0], ad[1], ad[2], ad[3]);
    #pragma unroll
    for (int k = 0; k < 16; k++) {
      xb32[v * 32 + 2 * k]     = pk2(xq[k].x, xq[k].y);
      xb32[v * 32 + 2 * k + 1] = pk2(xq[k].z, xq[k].w);
    }
  }
}

// -------- scans over PADDED degrees (each node region rounded to mult of 8) --------
__global__ void k_scan1(const int* __restrict__ deg, int N, int* __restrict__ part,
                        int* __restrict__ bsum) {
  __shared__ int tmp[1024];
  int tid = threadIdx.x;
  int i = blockIdx.x * 1024 + tid;
  int dv = (i < N) ? deg[i] : 0;
  int v = (dv + 7) & ~7;                       // padded degree
  tmp[tid] = v;
  __syncthreads();
  for (int ofs = 1; ofs < 1024; ofs <<= 1) {
    int t = (tid >= ofs) ? tmp[tid - ofs] : 0;
    __syncthreads();
    tmp[tid] += t;
    __syncthreads();
  }
  if (i < N) part[i] = tmp[tid] - v;
  if (tid == 1023) bsum[blockIdx.x] = tmp[tid];
}

__global__ void k_scan2(int* __restrict__ part, const int* __restrict__ bsum,
                        const int* __restrict__ deg, int N, int* __restrict__ cursor) {
  __shared__ int sbase;
  if (threadIdx.x == 0) {
    int b = 0;
    for (int j = 0; j < (int)blockIdx.x; j++) b += bsum[j];
    sbase = b;
  }
  __syncthreads();
  int i = blockIdx.x * 1024 + threadIdx.x;
  if (i < N) {
    int o = part[i] + sbase;
    part[i] = o;                               // part == offsets
    cursor[i] = o;
    if (i == N - 1) part[N] = o + ((deg[i] + 7) & ~7);
  }
}

// -------- pad slots -> safe ids (0, E) with zero guard weight; no memsets --------
__global__ void k_pad(const int* __restrict__ offsets, const int* __restrict__ deg,
                      int2* __restrict__ csr2, float4* __restrict__ att_eo,
                      int N, int E) {
  int v = blockIdx.x * blockDim.x + threadIdx.x;
  if (v == 0) att_eo[E] = make_float4(0.f, 0.f, 0.f, 0.f);   // guard: zero weight
  if (v < N) {
    const int o = offsets[v], d = deg[v];
    const int pe = o + ((d + 7) & ~7);
    for (int s = o + d; s < pe; s++) csr2[s] = make_int2(0, E);
  }
}

// -------- fill: attention weight in EDGE order (contiguous) + CSR slot scatter ----
__launch_bounds__(256)
__global__ void k_fill3(const int* __restrict__ esrc, const int* __restrict__ edst, int E,
                        const float* __restrict__ ea, const float4* __restrict__ A_s,
                        const float4* __restrict__ A_d, const float* __restrict__ W_att,
                        int* __restrict__ cursor, int2* __restrict__ csr2,
                        float4* __restrict__ att_eo) {
  __shared__ float4 s_we[32];                  // W_att[:,128:160]: 4 heads x 8 float4
  if (threadIdx.x < 32) {
    int h = threadIdx.x >> 3, k4 = threadIdx.x & 7;
    const float* p = &W_att[h * 160 + 128 + k4 * 4];
    s_we[threadIdx.x] = make_float4(p[0], p[1], p[2], p[3]);
  }
  __syncthreads();
  for (int e = blockIdx.x * blockDim.x + threadIdx.x; e < E; e += gridDim.x * blockDim.x) {
    const int s = esrc[e], d = edst[e];
    const int slot = atomicAdd(&cursor[d], 1);
    const float4* ep = (const float4*)&ea[(unsigned)e * 32u];
    float4 eq[8];
    #pragma unroll
    for (int k = 0; k < 8; k++) eq[k] = ep[k];
    const float4 as4 = A_s[s], ad4 = A_d[d];
    const float base[4] = {as4.x + ad4.x, as4.y + ad4.y, as4.z + ad4.z, as4.w + ad4.w};
    float av[4];
    #pragma unroll
    for (int h = 0; h < 4; h++) {
      float lg = base[h];
      #pragma unroll
      for (int k = 0; k < 8; k++) lg += dot4(s_we[h * 8 + k], eq[k]);
      lg = fmaxf(lg, 0.2f * lg);               // leaky relu
      av[h] = __expf(lg);
    }
    att_eo[e] = make_float4(av[0], av[1], av[2], av[3]);  // contiguous write
    csr2[slot] = make_int2(s, e);                         // the only scatter
  }
}

// -------- aggregation: lean gather-FMA; att gathered per edge (broadcast load) ----
__launch_bounds__(256)
__global__ void k_agg2(const unsigned short* __restrict__ xb, const float* __restrict__ ea,
                       const int2* __restrict__ csr2, const float4* __restrict__ att_eo,
                       const int* __restrict__ offsets,
                       unsigned short* __restrict__ agg, float* __restrict__ denom, int N) {
  __shared__ int2 s_ids[4][32];                // wave-private id quad
  const int lane = threadIdx.x & 63;
  const int wvb = threadIdx.x >> 6;
  const int wv = (blockIdx.x * blockDim.x + threadIdx.x) >> 6;
  const int nw = (gridDim.x * blockDim.x) >> 6;
  const int l32 = lane & 31;
  const bool hi = lane >= 32;

  for (int v0 = wv; v0 < N; v0 += nw) {
    const int vv = __builtin_amdgcn_readfirstlane(v0);
    const int sstart = __builtin_amdgcn_readfirstlane(offsets[vv]);
    const int send = __builtin_amdgcn_readfirstlane(offsets[vv + 1]);
    const int ng = (send - sstart) >> 3;

    float ax0 = 0, ax1 = 0, ax2 = 0, ax3 = 0;
    float ae0 = 0, ae1 = 0, ae2 = 0, ae3 = 0;
    float dn0 = 0, dn1 = 0, dn2 = 0, dn3 = 0;

    if (ng > 0) {
      {
        int2 q_ = csr2[sstart + l32];
        if (lane < 32) s_ids[wvb][l32] = q_;
      }
      for (int g = 0; g < ng; g++) {
        if (g > 0 && (g & 3) == 0) {           // rare (deg > 32)
          int2 q_ = csr2[sstart + g * 8 + l32];
          if (lane < 32) s_ids[wvb][l32] = q_;
        }
        const int qo = (g & 3) * 8;
        // edge ids (uniform LDS reads)
        const int2 t0 = s_ids[wvb][qo + 0], t1 = s_ids[wvb][qo + 1];
        const int2 t2 = s_ids[wvb][qo + 2], t3 = s_ids[wvb][qo + 3];
        const int2 t4 = s_ids[wvb][qo + 4], t5 = s_ids[wvb][qo + 5];
        const int2 t6 = s_ids[wvb][qo + 6], t7 = s_ids[wvb][qo + 7];
        // attention weights: per-edge broadcast loads from edge-order table
        const float4 at0 = att_eo[(unsigned)t0.y];
        const float4 at1 = att_eo[(unsigned)t1.y];
        const float4 at2 = att_eo[(unsigned)t2.y];
        const float4 at3 = att_eo[(unsigned)t3.y];
        const float4 at4 = att_eo[(unsigned)t4.y];
        const float4 at5 = att_eo[(unsigned)t5.y];
        const float4 at6 = att_eo[(unsigned)t6.y];
        const float4 at7 = att_eo[(unsigned)t7.y];
        // gathers (32-bit offsets)
        const unsigned short q0 = xb[(unsigned)(t0.x << 6) + lane];
        const unsigned short q1 = xb[(unsigned)(t1.x << 6) + lane];
        const unsigned short q2 = xb[(unsigned)(t2.x << 6) + lane];
        const unsigned short q3 = xb[(unsigned)(t3.x << 6) + lane];
        const unsigned short q4 = xb[(unsigned)(t4.x << 6) + lane];
        const unsigned short q5 = xb[(unsigned)(t5.x << 6) + lane];
        const unsigned short q6 = xb[(unsigned)(t6.x << 6) + lane];
        const unsigned short q7 = xb[(unsigned)(t7.x << 6) + lane];
        const float e0 = ea[(unsigned)(t0.y << 5) + l32];
        const float e1 = ea[(unsigned)(t1.y << 5) + l32];
        const float e2 = ea[(unsigned)(t2.y << 5) + l32];
        const float e3 = ea[(unsigned)(t3.y << 5) + l32];
        const float e4 = ea[(unsigned)(t4.y << 5) + l32];
        const float e5 = ea[(unsigned)(t5.y << 5) + l32];
        const float e6 = ea[(unsigned)(t6.y << 5) + l32];
        const float e7 = ea[(unsigned)(t7.y << 5) + l32];
        // accumulate
        float xf;
#define ACC(AT, Q, EV)                                                      \
        xf = ubf((unsigned)Q);                                              \
        ax0 = fmaf(AT.x, xf, ax0); ax1 = fmaf(AT.y, xf, ax1);               \
        ax2 = fmaf(AT.z, xf, ax2); ax3 = fmaf(AT.w, xf, ax3);               \
        ae0 = fmaf(AT.x, EV, ae0); ae1 = fmaf(AT.y, EV, ae1);               \
        ae2 = fmaf(AT.z, EV, ae2); ae3 = fmaf(AT.w, EV, ae3);               \
        dn0 += AT.x; dn1 += AT.y; dn2 += AT.z; dn3 += AT.w;
        ACC(at0, q0, e0) ACC(at1, q1, e1) ACC(at2, q2, e2) ACC(at3, q3, e3)
        ACC(at4, q4, e4) ACC(at5, q5, e5) ACC(at6, q6, e6) ACC(at7, q7, e7)
#undef ACC
      }
    }

    const unsigned base = (unsigned)v0 * 384u;
    agg[base + lane]        = fbf(ax0);
    agg[base + 96 + lane]   = fbf(ax1);
    agg[base + 192 + lane]  = fbf(ax2);
    agg[base + 288 + lane]  = fbf(ax3);
    const int hA = hi ? 2 : 0;
    agg[base + hA * 96 + 64 + l32]       = fbf(hi ? ae2 : ae0);
    agg[base + (hA + 1) * 96 + 64 + l32] = fbf(hi ? ae3 : ae1);
    if (lane == 0) ((float4*)denom)[v0] = make_float4(dn0, dn1, dn2, dn3);
  }
}

// ---------------- out = blockdiag(W_msg) * agg, /denom, +bias, LN ----------------
__launch_bounds__(128)
__global__ void k_out(const unsigned short* __restrict__ agg, const float* __restrict__ W_msg,
                      const float* __restrict__ denom, const float* __restrict__ bias,
                      const float* __restrict__ gamma, const float* __restrict__ beta,
                      float* __restrict__ out, int N, int T) {
  __shared__ float s_den[64];
  __shared__ float s_sum[2][16], s_sq[2][16];
  const int f = threadIdx.x;
  const int w = f >> 6;            // wave: heads 2w, 2w+1 -> cols 64w..64w+63
  const int l = f & 63;
  const int c16 = l & 15;
  const int rg = l >> 4;

  short8 wb[2][2][3];
  float biasv[2][2], gv[2][2], bv[2][2];
  #pragma unroll
  for (int hh = 0; hh < 2; hh++) {
    const int head = 2 * w + hh;
    #pragma unroll
    for (int ct = 0; ct < 2; ct++) {
      const int q = head * 32 + ct * 16 + c16;
      biasv[hh][ct] = bias[q]; gv[hh][ct] = gamma[q]; bv[hh][ct] = beta[q];
      #pragma unroll
      for (int kk = 0; kk < 3; kk++) {
        const float* p = &W_msg[q * 96 + kk * 32 + rg * 8];
        short8 s;
        #pragma unroll
        for (int i = 0; i < 8; i++) s[i] = (short)fbf(p[i]);
        wb[hh][ct][kk] = s;
      }
    }
  }

  for (int t = blockIdx.x; t < T; t += gridDim.x) {
    const int n0 = t * 16;
    if (f < 64) s_den[f] = denom[min(n0 + (f >> 2), N - 1) * 4 + (f & 3)];
    __syncthreads();

    f32x4 c[2][2] = {{{0.f,0.f,0.f,0.f},{0.f,0.f,0.f,0.f}},
                     {{0.f,0.f,0.f,0.f},{0.f,0.f,0.f,0.f}}};
    const int nA = min(n0 + c16, N - 1);
    #pragma unroll
    for (int hh = 0; hh < 2; hh++) {
      const int head = 2 * w + hh;
      #pragma unroll
      for (int kk = 0; kk < 3; kk++) {
        short8 a = *(const short8*)&agg[nA * 384 + head * 96 + kk * 32 + rg * 8];
        c[hh][0] = __builtin_amdgcn_mfma_f32_16x16x32_bf16(a, wb[hh][0][kk], c[hh][0], 0, 0, 0);
        c[hh][1] = __builtin_amdgcn_mfma_f32_16x16x32_bf16(a, wb[hh][1][kk], c[hh][1], 0, 0, 0);
      }
    }

    float val[2][2][4];
    #pragma unroll
    for (int hh = 0; hh < 2; hh++)
      #pragma unroll
      for (int ct = 0; ct < 2; ct++)
        #pragma unroll
        for (int r = 0; r < 4; r++) {
          const float d = s_den[(rg * 4 + r) * 4 + (2 * w + hh)] + 1e-9f;
          val[hh][ct][r] = c[hh][ct][r] / d + biasv[hh][ct];
        }

    float sr[4], qr[4];
    #pragma unroll
    for (int r = 0; r < 4; r++) {
      float s = 0.f, q2 = 0.f;
      #pragma unroll
      for (int hh = 0; hh < 2; hh++)
        #pragma unroll
        for (int ct = 0; ct < 2; ct++) { s += val[hh][ct][r]; q2 = fmaf(val[hh][ct][r], val[hh][ct][r], q2); }
      #pragma unroll
      for (int m = 1; m <= 8; m <<= 1) { s += __shfl_xor(s, m, 64); q2 += __shfl_xor(q2, m, 64); }
      sr[r] = s; qr[r] = q2;
    }
    if (c16 == 0) {
      #pragma unroll
      for (int r = 0; r < 4; r++) { s_sum[w][rg * 4 + r] = sr[r]; s_sq[w][rg * 4 + r] = qr[r]; }
    }
    __syncthreads();

    float mean[4], rstd[4];
    #pragma unroll
    for (int r = 0; r < 4; r++) {
      const int ni = rg * 4 + r;
      mean[r] = (s_sum[0][ni] + s_sum[1][ni]) * (1.f / 128.f);
      const float m2 = (s_sq[0][ni] + s_sq[1][ni]) * (1.f / 128.f);
      rstd[r] = rsqrtf(m2 - mean[r] * mean[r] + 1e-5f);
    }
    #pragma unroll
    for (int hh = 0; hh < 2; hh++)
      #pragma unroll
      for (int ct = 0; ct < 2; ct++)
        #pragma unroll
        for (int r = 0; r < 4; r++) {
          const int n = n0 + rg * 4 + r;
          if (n < N)
            out[n * 128 + (2 * w + hh) * 32 + ct * 16 + c16] =
                (val[hh][ct][r] - mean[r]) * rstd[r] * gv[hh][ct] + bv[hh][ct];
        }
    __syncthreads();
  }
}

extern "C" void kernel_launch(void* const* d_in, const int* in_sizes, int n_in,
                              void* d_out, int out_size, void* d_ws, size_t ws_size,
                              hipStream_t stream) {
  const float* x     = (const float*)d_in[0];
  const int*   ei    = (const int*)d_in[1];
  const float* ea    = (const float*)d_in[2];
  const float* W_msg = (const float*)d_in[3];
  const float* W_att = (const float*)d_in[4];
  const float* bias  = (const float*)d_in[5];
  const float* gamma = (const float*)d_in[6];
  const float* beta  = (const float*)d_in[7];
  float* out = (float*)d_out;

  const int N = in_sizes[0] / 64;
  const int E = in_sizes[1] / 2;
  const int* esrc = ei;
  const int* edst = ei + E;
  const int EP = E + 8 * N + 64;               // padded-CSR capacity

  char* p = (char*)d_ws;
  int* deg      = (int*)p;            p += (size_t)N * 4;
  int* offsets  = (int*)p;            p += (size_t)(N + 1) * 4;
  int* cursor   = (int*)p;            p += (size_t)N * 4;
  int* bsum     = (int*)p;            p += 2048 * 4;
  int2* csr2    = (int2*)p;           p += (size_t)EP * 8;
  float4* att_eo = (float4*)p;        p += (size_t)(E + 8) * 16;
  float4* A_s   = (float4*)p;         p += (size_t)N * 16;
  float4* A_d   = (float4*)p;         p += (size_t)N * 16;
  unsigned short* xb = (unsigned short*)p; p += (size_t)N * 64 * 2;
  unsigned short* agg = (unsigned short*)p; p += (size_t)N * 384 * 2;
  float* denom  = (float*)p;

  hipMemsetAsync(deg, 0, (size_t)N * 4, stream);
  const int SB = (N + 1023) / 1024;
  const int T = (N + 15) / 16;

  k_phase1<<<2048, 256, 0, stream>>>(x, W_att, edst, E, A_s, A_d, (unsigned*)xb, deg, N);
  k_scan1<<<SB, 1024, 0, stream>>>(deg, N, offsets, bsum);
  k_scan2<<<SB, 1024, 0, stream>>>(offsets, bsum, deg, N, cursor);
  k_pad<<<(N + 255) / 256, 256, 0, stream>>>(offsets, deg, csr2, att_eo, N, E);
  k_fill3<<<2048, 256, 0, stream>>>(esrc, edst, E, ea, A_s, A_d, W_att, cursor, csr2, att_eo);
  k_agg2<<<2048, 256, 0, stream>>>(xb, ea, csr2, att_eo, offsets, agg, denom, N);
  k_out<<<T, 128, 0, stream>>>(agg, W_msg, denom, bias, gamma, beta, out, N, T);
}

// Round 11
// 396.269 us; speedup vs baseline: 1.1660x; 1.1660x over previous
//
#include <hip/hip_runtime.h>
#include <hip/hip_bf16.h>

typedef __attribute__((ext_vector_type(8))) short short8;
typedef __attribute__((ext_vector_type(4))) float f32x4;

__device__ __forceinline__ unsigned short fbf(float f) {
  union { float f; unsigned u; } v; v.f = f;
  unsigned r = v.u + 0x7fffu + ((v.u >> 16) & 1u);   // RNE
  return (unsigned short)(r >> 16);
}
__device__ __forceinline__ unsigned pk2(float a, float b) {
  return (unsigned)fbf(a) | ((unsigned)fbf(b) << 16);
}
__device__ __forceinline__ float ubf(unsigned hi) {   // bf16 bits (low16) -> float
  union { unsigned u; float f; } v; v.u = hi << 16; return v.f;
}
__device__ __forceinline__ float ubf_lo(unsigned u) { // low16 bf16 -> float
  union { unsigned u; float f; } v; v.u = u << 16; return v.f;
}
__device__ __forceinline__ float ubf_hi(unsigned u) { // high16 bf16 -> float
  union { unsigned u; float f; } v; v.u = u & 0xffff0000u; return v.f;
}
__device__ __forceinline__ float dot4(float4 a, float4 b) {
  return fmaf(a.x, b.x, fmaf(a.y, b.y, fmaf(a.z, b.z, a.w * b.w)));
}

// -------- phase1: degree count + A_s/A_d tables + x->bf16 (single x pass) --------
__launch_bounds__(256)
__global__ void k_phase1(const float* __restrict__ x, const float* __restrict__ W_att,
                         const int* __restrict__ edst, int E,
                         float4* __restrict__ A_s, float4* __restrict__ A_d,
                         unsigned* __restrict__ xb32, int* __restrict__ deg, int N) {
  __shared__ float4 s_wa[160];                 // 4 heads x 40 float4 (row len 160)
  if (threadIdx.x < 160) s_wa[threadIdx.x] = ((const float4*)W_att)[threadIdx.x];
  for (int i = blockIdx.x * blockDim.x + threadIdx.x; i < E; i += gridDim.x * blockDim.x)
    atomicAdd(&deg[edst[i]], 1);
  __syncthreads();
  for (int v = blockIdx.x * blockDim.x + threadIdx.x; v < N; v += gridDim.x * blockDim.x) {
    const float4* xp = (const float4*)&x[v * 64];
    float4 xq[16];
    #pragma unroll
    for (int k = 0; k < 16; k++) xq[k] = xp[k];
    float as[4] = {}, ad[4] = {};
    #pragma unroll
    for (int h = 0; h < 4; h++) {
      #pragma unroll
      for (int k = 0; k < 16; k++) {
        as[h] += dot4(s_wa[h * 40 + k], xq[k]);
        ad[h] += dot4(s_wa[h * 40 + 16 + k], xq[k]);
      }
    }
    A_s[v] = make_float4(as[0], as[1], as[2], as[3]);
    A_d[v] = make_float4(ad[0], ad[1], ad[2], ad[3]);
    #pragma unroll
    for (int k = 0; k < 16; k++) {
      xb32[v * 32 + 2 * k]     = pk2(xq[k].x, xq[k].y);
      xb32[v * 32 + 2 * k + 1] = pk2(xq[k].z, xq[k].w);
    }
  }
}

// -------- scans over PADDED degrees (each node region rounded to mult of 8) --------
__global__ void k_scan1(const int* __restrict__ deg, int N, int* __restrict__ part,
                        int* __restrict__ bsum) {
  __shared__ int tmp[1024];
  int tid = threadIdx.x;
  int i = blockIdx.x * 1024 + tid;
  int dv = (i < N) ? deg[i] : 0;
  int v = (dv + 7) & ~7;                       // padded degree
  tmp[tid] = v;
  __syncthreads();
  for (int ofs = 1; ofs < 1024; ofs <<= 1) {
    int t = (tid >= ofs) ? tmp[tid - ofs] : 0;
    __syncthreads();
    tmp[tid] += t;
    __syncthreads();
  }
  if (i < N) part[i] = tmp[tid] - v;
  if (tid == 1023) bsum[blockIdx.x] = tmp[tid];
}

// -------- scan finalize + write pad records inline (no k_pad, no memsets) --------
__global__ void k_scan2(int* __restrict__ part, const int* __restrict__ bsum,
                        const int* __restrict__ deg, int N, int* __restrict__ cursor,
                        int4* __restrict__ csrp) {
  __shared__ int sbase;
  if (threadIdx.x == 0) {
    int b = 0;
    for (int j = 0; j < (int)blockIdx.x; j++) b += bsum[j];
    sbase = b;
  }
  __syncthreads();
  int i = blockIdx.x * 1024 + threadIdx.x;
  if (i < N) {
    const int o = part[i] + sbase;
    part[i] = o;                               // part == offsets
    cursor[i] = o;
    const int d = deg[i];
    const int pe = o + ((d + 7) & ~7);
    const int4 z = make_int4(0, 0, 0, 0);      // att=0 -> no contribution
    for (int s = o + d; s < pe; s++) csrp[s] = z;
    if (i == N - 1) part[N] = pe;
  }
}

// -------- fill: att computed edge-order, packed {src,e,att(bf16x4)} single scatter --
__launch_bounds__(256)
__global__ void k_fillP(const int* __restrict__ esrc, const int* __restrict__ edst, int E,
                        const float* __restrict__ ea, const float4* __restrict__ A_s,
                        const float4* __restrict__ A_d, const float* __restrict__ W_att,
                        int* __restrict__ cursor, int4* __restrict__ csrp) {
  __shared__ float4 s_we[32];                  // W_att[:,128:160]: 4 heads x 8 float4
  if (threadIdx.x < 32) {
    int h = threadIdx.x >> 3, k4 = threadIdx.x & 7;
    const float* p = &W_att[h * 160 + 128 + k4 * 4];
    s_we[threadIdx.x] = make_float4(p[0], p[1], p[2], p[3]);
  }
  __syncthreads();
  for (int e = blockIdx.x * blockDim.x + threadIdx.x; e < E; e += gridDim.x * blockDim.x) {
    const int s = esrc[e], d = edst[e];
    const int slot = atomicAdd(&cursor[d], 1);
    const float4* ep = (const float4*)&ea[(unsigned)e * 32u];
    float4 eq[8];
    #pragma unroll
    for (int k = 0; k < 8; k++) eq[k] = ep[k];
    const float4 as4 = A_s[s], ad4 = A_d[d];
    const float base[4] = {as4.x + ad4.x, as4.y + ad4.y, as4.z + ad4.z, as4.w + ad4.w};
    float av[4];
    #pragma unroll
    for (int h = 0; h < 4; h++) {
      float lg = base[h];
      #pragma unroll
      for (int k = 0; k < 8; k++) lg += dot4(s_we[h * 8 + k], eq[k]);
      lg = fmaxf(lg, 0.2f * lg);               // leaky relu
      av[h] = __expf(lg);
    }
    csrp[slot] = make_int4(s, e, (int)pk2(av[0], av[1]), (int)pk2(av[2], av[3]));
  }
}

// -------- aggregation: packed slot stream; att free with ids; gather-FMA --------
__launch_bounds__(256)
__global__ void k_aggP(const unsigned short* __restrict__ xb, const float* __restrict__ ea,
                       const int4* __restrict__ csrp, const int* __restrict__ offsets,
                       unsigned short* __restrict__ agg, float* __restrict__ denom, int N) {
  __shared__ int4 s_ids[4][32];                // wave-private slot quad
  const int lane = threadIdx.x & 63;
  const int wvb = threadIdx.x >> 6;
  const int wv = (blockIdx.x * blockDim.x + threadIdx.x) >> 6;
  const int nw = (gridDim.x * blockDim.x) >> 6;
  const int l32 = lane & 31;
  const bool hi = lane >= 32;

  for (int v0 = wv; v0 < N; v0 += nw) {
    const int vv = __builtin_amdgcn_readfirstlane(v0);
    const int sstart = __builtin_amdgcn_readfirstlane(offsets[vv]);
    const int send = __builtin_amdgcn_readfirstlane(offsets[vv + 1]);
    const int ng = (send - sstart) >> 3;

    float ax0 = 0, ax1 = 0, ax2 = 0, ax3 = 0;
    float ae0 = 0, ae1 = 0, ae2 = 0, ae3 = 0;
    float dn0 = 0, dn1 = 0, dn2 = 0, dn3 = 0;

    if (ng > 0) {
      {
        int4 q_ = csrp[sstart + l32];
        if (lane < 32) s_ids[wvb][l32] = q_;
      }
      for (int g = 0; g < ng; g++) {
        if (g > 0 && (g & 3) == 0) {           // rare (deg > 32)
          int4 q_ = csrp[sstart + g * 8 + l32];
          if (lane < 32) s_ids[wvb][l32] = q_;
        }
        const int qo = (g & 3) * 8;
        // slot records (uniform LDS reads)
        const int4 t0 = s_ids[wvb][qo + 0], t1 = s_ids[wvb][qo + 1];
        const int4 t2 = s_ids[wvb][qo + 2], t3 = s_ids[wvb][qo + 3];
        const int4 t4 = s_ids[wvb][qo + 4], t5 = s_ids[wvb][qo + 5];
        const int4 t6 = s_ids[wvb][qo + 6], t7 = s_ids[wvb][qo + 7];
        // gathers (32-bit offsets)
        const unsigned short q0 = xb[(unsigned)(t0.x << 6) + lane];
        const unsigned short q1 = xb[(unsigned)(t1.x << 6) + lane];
        const unsigned short q2 = xb[(unsigned)(t2.x << 6) + lane];
        const unsigned short q3 = xb[(unsigned)(t3.x << 6) + lane];
        const unsigned short q4 = xb[(unsigned)(t4.x << 6) + lane];
        const unsigned short q5 = xb[(unsigned)(t5.x << 6) + lane];
        const unsigned short q6 = xb[(unsigned)(t6.x << 6) + lane];
        const unsigned short q7 = xb[(unsigned)(t7.x << 6) + lane];
        const float e0 = ea[(unsigned)(t0.y << 5) + l32];
        const float e1 = ea[(unsigned)(t1.y << 5) + l32];
        const float e2 = ea[(unsigned)(t2.y << 5) + l32];
        const float e3 = ea[(unsigned)(t3.y << 5) + l32];
        const float e4 = ea[(unsigned)(t4.y << 5) + l32];
        const float e5 = ea[(unsigned)(t5.y << 5) + l32];
        const float e6 = ea[(unsigned)(t6.y << 5) + l32];
        const float e7 = ea[(unsigned)(t7.y << 5) + l32];
        // accumulate (att unpacked from the slot record)
        float xf, a0_, a1_, a2_, a3_;
#define ACC(T, Q, EV)                                                       \
        a0_ = ubf_lo((unsigned)T.z); a1_ = ubf_hi((unsigned)T.z);           \
        a2_ = ubf_lo((unsigned)T.w); a3_ = ubf_hi((unsigned)T.w);           \
        xf = ubf((unsigned)Q);                                              \
        ax0 = fmaf(a0_, xf, ax0); ax1 = fmaf(a1_, xf, ax1);                 \
        ax2 = fmaf(a2_, xf, ax2); ax3 = fmaf(a3_, xf, ax3);                 \
        ae0 = fmaf(a0_, EV, ae0); ae1 = fmaf(a1_, EV, ae1);                 \
        ae2 = fmaf(a2_, EV, ae2); ae3 = fmaf(a3_, EV, ae3);                 \
        dn0 += a0_; dn1 += a1_; dn2 += a2_; dn3 += a3_;
        ACC(t0, q0, e0) ACC(t1, q1, e1) ACC(t2, q2, e2) ACC(t3, q3, e3)
        ACC(t4, q4, e4) ACC(t5, q5, e5) ACC(t6, q6, e6) ACC(t7, q7, e7)
#undef ACC
      }
    }

    const unsigned base = (unsigned)v0 * 384u;
    agg[base + lane]        = fbf(ax0);
    agg[base + 96 + lane]   = fbf(ax1);
    agg[base + 192 + lane]  = fbf(ax2);
    agg[base + 288 + lane]  = fbf(ax3);
    const int hA = hi ? 2 : 0;
    agg[base + hA * 96 + 64 + l32]       = fbf(hi ? ae2 : ae0);
    agg[base + (hA + 1) * 96 + 64 + l32] = fbf(hi ? ae3 : ae1);
    if (lane == 0) ((float4*)denom)[v0] = make_float4(dn0, dn1, dn2, dn3);
  }
}

// ---------------- out = blockdiag(W_msg) * agg, /denom, +bias, LN ----------------
__launch_bounds__(128)
__global__ void k_out(const unsigned short* __restrict__ agg, const float* __restrict__ W_msg,
                      const float* __restrict__ denom, const float* __restrict__ bias,
                      const float* __restrict__ gamma, const float* __restrict__ beta,
                      float* __restrict__ out, int N, int T) {
  __shared__ float s_den[64];
  __shared__ float s_sum[2][16], s_sq[2][16];
  const int f = threadIdx.x;
  const int w = f >> 6;            // wave: heads 2w, 2w+1 -> cols 64w..64w+63
  const int l = f & 63;
  const int c16 = l & 15;
  const int rg = l >> 4;

  short8 wb[2][2][3];
  float biasv[2][2], gv[2][2], bv[2][2];
  #pragma unroll
  for (int hh = 0; hh < 2; hh++) {
    const int head = 2 * w + hh;
    #pragma unroll
    for (int ct = 0; ct < 2; ct++) {
      const int q = head * 32 + ct * 16 + c16;
      biasv[hh][ct] = bias[q]; gv[hh][ct] = gamma[q]; bv[hh][ct] = beta[q];
      #pragma unroll
      for (int kk = 0; kk < 3; kk++) {
        const float* p = &W_msg[q * 96 + kk * 32 + rg * 8];
        short8 s;
        #pragma unroll
        for (int i = 0; i < 8; i++) s[i] = (short)fbf(p[i]);
        wb[hh][ct][kk] = s;
      }
    }
  }

  for (int t = blockIdx.x; t < T; t += gridDim.x) {
    const int n0 = t * 16;
    if (f < 64) s_den[f] = denom[min(n0 + (f >> 2), N - 1) * 4 + (f & 3)];
    __syncthreads();

    f32x4 c[2][2] = {{{0.f,0.f,0.f,0.f},{0.f,0.f,0.f,0.f}},
                     {{0.f,0.f,0.f,0.f},{0.f,0.f,0.f,0.f}}};
    const int nA = min(n0 + c16, N - 1);
    #pragma unroll
    for (int hh = 0; hh < 2; hh++) {
      const int head = 2 * w + hh;
      #pragma unroll
      for (int kk = 0; kk < 3; kk++) {
        short8 a = *(const short8*)&agg[nA * 384 + head * 96 + kk * 32 + rg * 8];
        c[hh][0] = __builtin_amdgcn_mfma_f32_16x16x32_bf16(a, wb[hh][0][kk], c[hh][0], 0, 0, 0);
        c[hh][1] = __builtin_amdgcn_mfma_f32_16x16x32_bf16(a, wb[hh][1][kk], c[hh][1], 0, 0, 0);
      }
    }

    float val[2][2][4];
    #pragma unroll
    for (int hh = 0; hh < 2; hh++)
      #pragma unroll
      for (int ct = 0; ct < 2; ct++)
        #pragma unroll
        for (int r = 0; r < 4; r++) {
          const float d = s_den[(rg * 4 + r) * 4 + (2 * w + hh)] + 1e-9f;
          val[hh][ct][r] = c[hh][ct][r] / d + biasv[hh][ct];
        }

    float sr[4], qr[4];
    #pragma unroll
    for (int r = 0; r < 4; r++) {
      float s = 0.f, q2 = 0.f;
      #pragma unroll
      for (int hh = 0; hh < 2; hh++)
        #pragma unroll
        for (int ct = 0; ct < 2; ct++) { s += val[hh][ct][r]; q2 = fmaf(val[hh][ct][r], val[hh][ct][r], q2); }
      #pragma unroll
      for (int m = 1; m <= 8; m <<= 1) { s += __shfl_xor(s, m, 64); q2 += __shfl_xor(q2, m, 64); }
      sr[r] = s; qr[r] = q2;
    }
    if (c16 == 0) {
      #pragma unroll
      for (int r = 0; r < 4; r++) { s_sum[w][rg * 4 + r] = sr[r]; s_sq[w][rg * 4 + r] = qr[r]; }
    }
    __syncthreads();

    float mean[4], rstd[4];
    #pragma unroll
    for (int r = 0; r < 4; r++) {
      const int ni = rg * 4 + r;
      mean[r] = (s_sum[0][ni] + s_sum[1][ni]) * (1.f / 128.f);
      const float m2 = (s_sq[0][ni] + s_sq[1][ni]) * (1.f / 128.f);
      rstd[r] = rsqrtf(m2 - mean[r] * mean[r] + 1e-5f);
    }
    #pragma unroll
    for (int hh = 0; hh < 2; hh++)
      #pragma unroll
      for (int ct = 0; ct < 2; ct++)
        #pragma unroll
        for (int r = 0; r < 4; r++) {
          const int n = n0 + rg * 4 + r;
          if (n < N)
            out[n * 128 + (2 * w + hh) * 32 + ct * 16 + c16] =
                (val[hh][ct][r] - mean[r]) * rstd[r] * gv[hh][ct] + bv[hh][ct];
        }
    __syncthreads();
  }
}

extern "C" void kernel_launch(void* const* d_in, const int* in_sizes, int n_in,
                              void* d_out, int out_size, void* d_ws, size_t ws_size,
                              hipStream_t stream) {
  const float* x     = (const float*)d_in[0];
  const int*   ei    = (const int*)d_in[1];
  const float* ea    = (const float*)d_in[2];
  const float* W_msg = (const float*)d_in[3];
  const float* W_att = (const float*)d_in[4];
  const float* bias  = (const float*)d_in[5];
  const float* gamma = (const float*)d_in[6];
  const float* beta  = (const float*)d_in[7];
  float* out = (float*)d_out;

  const int N = in_sizes[0] / 64;
  const int E = in_sizes[1] / 2;
  const int* esrc = ei;
  const int* edst = ei + E;
  const int EP = E + 8 * N + 64;               // padded-CSR capacity

  char* p = (char*)d_ws;
  int* deg      = (int*)p;            p += (size_t)N * 4;
  int* offsets  = (int*)p;            p += (size_t)(N + 1) * 4;
  int* cursor   = (int*)p;            p += (size_t)N * 4;
  int* bsum     = (int*)p;            p += 2048 * 4;
  int4* csrp    = (int4*)p;           p += (size_t)EP * 16;
  float4* A_s   = (float4*)p;         p += (size_t)N * 16;
  float4* A_d   = (float4*)p;         p += (size_t)N * 16;
  unsigned short* xb = (unsigned short*)p; p += (size_t)N * 64 * 2;
  unsigned short* agg = (unsigned short*)p; p += (size_t)N * 384 * 2;
  float* denom  = (float*)p;

  hipMemsetAsync(deg, 0, (size_t)N * 4, stream);
  const int SB = (N + 1023) / 1024;
  const int T = (N + 15) / 16;

  k_phase1<<<2048, 256, 0, stream>>>(x, W_att, edst, E, A_s, A_d, (unsigned*)xb, deg, N);
  k_scan1<<<SB, 1024, 0, stream>>>(deg, N, offsets, bsum);
  k_scan2<<<SB, 1024, 0, stream>>>(offsets, bsum, deg, N, cursor, csrp);
  k_fillP<<<2048, 256, 0, stream>>>(esrc, edst, E, ea, A_s, A_d, W_att, cursor, csrp);
  k_aggP<<<2048, 256, 0, stream>>>(xb, ea, csrp, offsets, agg, denom, N);
  k_out<<<T, 128, 0, stream>>>(agg, W_msg, denom, bias, gamma, beta, out, N, T);
}